// Round 8
// baseline (407.817 us; speedup 1.0000x reference)
//
#include <hip/hip_runtime.h>
#include <hip/hip_bf16.h>

// GNN: 2-layer GCN (N=50000, E=800000, F=128, H=256) + mean-pool (G=512) + MLP head (257->32->4)
// Identity 1 (linearity): agg-then-GEMM per layer.
// Identity 2 (norm factoring): out[d] = dinv[d]*(sum_e in_s[src] + in_s[d]), in_s = dinv*in,
//   so CSR needs only src indices (4B/edge) and agg is plain adds.
// R7: MFMA GEMMs (372us). R8: XCD column-sliced aggregation (blockIdx%8 -> XCD round-robin;
//   slice 0 on XCD 0-3, slice 1 on XCD 4-7 halves per-XCD unique bytes: fetch 190->~100MB),
//   pre-scaled bf16 payloads, int-only CSR, bf16 h2.

#define NN 50000
#define EE 800000
#define FDIM 128
#define HDIM 256
#define GG 512
#define SCAN_NB ((NN + 255) / 256)

typedef __attribute__((ext_vector_type(8))) short short8;     // 8 bf16 = 4 VGPRs (MFMA A/B frag)
typedef __attribute__((ext_vector_type(4))) float floatx4;    // MFMA C/D frag

__device__ __forceinline__ unsigned short f2bf(float f) {   // RNE
    unsigned u = __float_as_uint(f);
    return (unsigned short)((u + 0x7FFF + ((u >> 16) & 1)) >> 16);
}
__device__ __forceinline__ float bflo(unsigned v) { return __uint_as_float(v << 16); }
__device__ __forceinline__ float bfhi(unsigned v) { return __uint_as_float(v & 0xFFFF0000u); }
__device__ __forceinline__ float bf1(unsigned short v) { return __uint_as_float((unsigned)v << 16); }

// ---------------- prep kernels ----------------

__global__ void hist_kernel(const int* __restrict__ dst, int* __restrict__ deg, int e) {
    int i = blockIdx.x * blockDim.x + threadIdx.x;
    int stride = gridDim.x * blockDim.x;
    for (; i < e; i += stride) atomicAdd(&deg[dst[i]], 1);
}

__global__ __launch_bounds__(256) void scan_part(const int* __restrict__ deg,
                                                 int* __restrict__ row_off,
                                                 int* __restrict__ blk_sums,
                                                 float* __restrict__ dinv, int n) {
    __shared__ int s[256];
    int tid = threadIdx.x;
    int i = blockIdx.x * 256 + tid;
    int v = (i < n) ? deg[i] : 0;
    if (i < n) dinv[i] = rsqrtf((float)v + 1.0f);
    s[tid] = v;
    __syncthreads();
    #pragma unroll
    for (int off = 1; off < 256; off <<= 1) {
        int t = (tid >= off) ? s[tid - off] : 0;
        __syncthreads();
        s[tid] += t;
        __syncthreads();
    }
    if (i < n) row_off[i] = s[tid] - v;
    if (tid == 255) blk_sums[blockIdx.x] = s[255];
}

__global__ __launch_bounds__(256) void scan_sums(int* __restrict__ blk_sums, int nb) {
    __shared__ int s[256];
    int tid = threadIdx.x;
    int v = (tid < nb) ? blk_sums[tid] : 0;
    s[tid] = v;
    __syncthreads();
    #pragma unroll
    for (int off = 1; off < 256; off <<= 1) {
        int t = (tid >= off) ? s[tid - off] : 0;
        __syncthreads();
        s[tid] += t;
        __syncthreads();
    }
    if (tid < nb) blk_sums[tid] = s[tid] - v;
}

__global__ __launch_bounds__(256) void scan_add(int* __restrict__ row_off,
                                                const int* __restrict__ blk_sums,
                                                int* __restrict__ fill, int n, int e) {
    int i = blockIdx.x * 256 + threadIdx.x;
    if (i < n) {
        row_off[i] += blk_sums[blockIdx.x];
        fill[i] = 0;
    }
    if (i == 0) row_off[n] = e;
}

// CSR = src indices only (weights factored out via pre-scaling)
__global__ void scatter_kernel(const int* __restrict__ src, const int* __restrict__ dst,
                               const int* __restrict__ row_off, int* __restrict__ fill,
                               int* __restrict__ csr_src, int e) {
    int i = blockIdx.x * blockDim.x + threadIdx.x;
    int stride = gridDim.x * blockDim.x;
    for (; i < e; i += stride) {
        int s = src[i], d = dst[i];
        int pos = row_off[d] + atomicAdd(&fill[d], 1);
        csr_src[pos] = s;
    }
}

// x_s[i,c] = bf16(x[i,c] * dinv[i]); 4 consecutive elems share a row (128 % 4 == 0)
__global__ void cast_scale_bf16(const float* __restrict__ in, const float* __restrict__ dinv,
                                unsigned short* __restrict__ out, int count) {
    int i = (blockIdx.x * blockDim.x + threadIdx.x) * 4;
    int stride = gridDim.x * blockDim.x * 4;
    for (; i < count; i += stride) {
        float d = dinv[i >> 7];
        float4 v = *(const float4*)&in[i];
        ushort4 o;
        o.x = f2bf(v.x * d); o.y = f2bf(v.y * d); o.z = f2bf(v.z * d); o.w = f2bf(v.w * d);
        *(ushort4*)&out[i] = o;
    }
}

// Wt[n][k] = bf16(W[k][n])
__global__ void transpose_cast_bf16(const float* __restrict__ W, unsigned short* __restrict__ Wt,
                                    int K, int Nc) {
    int idx = blockIdx.x * blockDim.x + threadIdx.x;
    if (idx < K * Nc) {
        int nn = idx / K, k = idx - nn * K;
        Wt[idx] = f2bf(W[(size_t)k * Nc + nn]);
    }
}

// ---------------- XCD-sliced GCN aggregation ----------------
// out[d] = bf16(dinv[d] * (in_s[d] + sum_e in_s[src_e]))  — in_s pre-scaled bf16.
// Grid = 8 * ceil(ceil(n/4)/4). blockIdx%8 -> XCD (round-robin heuristic):
// slice = (b&7)>>2 (col half), node_block = (b>>3)*4 + (b&3). One wave per node.

// 256-col rows, slice = 128 cols, uint (2 cols) per lane
__global__ __launch_bounds__(256) void gcn_agg256_sliced(const unsigned short* __restrict__ in,
                                                         const int* __restrict__ row_off,
                                                         const int* __restrict__ csr_src,
                                                         const float* __restrict__ dinv,
                                                         unsigned short* __restrict__ out, int n) {
    int b = blockIdx.x;
    int xcd = b & 7;
    int slice = xcd >> 2;
    int node_block = (b >> 3) * 4 + (xcd & 3);
    int wave = threadIdx.x >> 6, lane = threadIdx.x & 63;
    int node = node_block * 4 + wave;
    if (node >= n) return;
    const unsigned short* base = in + slice * 128;
    unsigned hu = *(const unsigned*)&base[(size_t)node * 256 + lane * 2];
    float2 acc = {bflo(hu), bfhi(hu)};
    int beg = __builtin_amdgcn_readfirstlane(row_off[node]);
    int end = __builtin_amdgcn_readfirstlane(row_off[node + 1]);
    int e = beg;
    for (; (e & 3) && e < end; ++e) {     // align to int4
        unsigned u = *(const unsigned*)&base[(size_t)csr_src[e] * 256 + lane * 2];
        acc.x += bflo(u); acc.y += bfhi(u);
    }
    int nmain = (end - e) >> 2;
    if (nmain > 0) {
        const int4* cp = (const int4*)&csr_src[e];
        int4 q = cp[0];
        for (int it = 1; it < nmain; ++it) {
            int4 r = cp[it];                       // prefetch next 4 edges
            unsigned u0 = *(const unsigned*)&base[(size_t)q.x * 256 + lane * 2];
            unsigned u1 = *(const unsigned*)&base[(size_t)q.y * 256 + lane * 2];
            unsigned u2 = *(const unsigned*)&base[(size_t)q.z * 256 + lane * 2];
            unsigned u3 = *(const unsigned*)&base[(size_t)q.w * 256 + lane * 2];
            acc.x += bflo(u0); acc.y += bfhi(u0);
            acc.x += bflo(u1); acc.y += bfhi(u1);
            acc.x += bflo(u2); acc.y += bfhi(u2);
            acc.x += bflo(u3); acc.y += bfhi(u3);
            q = r;
        }
        {
            unsigned u0 = *(const unsigned*)&base[(size_t)q.x * 256 + lane * 2];
            unsigned u1 = *(const unsigned*)&base[(size_t)q.y * 256 + lane * 2];
            unsigned u2 = *(const unsigned*)&base[(size_t)q.z * 256 + lane * 2];
            unsigned u3 = *(const unsigned*)&base[(size_t)q.w * 256 + lane * 2];
            acc.x += bflo(u0); acc.y += bfhi(u0);
            acc.x += bflo(u1); acc.y += bfhi(u1);
            acc.x += bflo(u2); acc.y += bfhi(u2);
            acc.x += bflo(u3); acc.y += bfhi(u3);
        }
        e += nmain * 4;
    }
    for (; e < end; ++e) {
        unsigned u = *(const unsigned*)&base[(size_t)csr_src[e] * 256 + lane * 2];
        acc.x += bflo(u); acc.y += bfhi(u);
    }
    float di = dinv[node];
    unsigned o = (unsigned)f2bf(acc.x * di) | ((unsigned)f2bf(acc.y * di) << 16);
    *(unsigned*)&out[(size_t)node * 256 + slice * 128 + lane * 2] = o;
}

// 128-col rows, slice = 64 cols, ushort (1 col) per lane
__global__ __launch_bounds__(256) void gcn_agg128_sliced(const unsigned short* __restrict__ in,
                                                         const int* __restrict__ row_off,
                                                         const int* __restrict__ csr_src,
                                                         const float* __restrict__ dinv,
                                                         unsigned short* __restrict__ out, int n) {
    int b = blockIdx.x;
    int xcd = b & 7;
    int slice = xcd >> 2;
    int node_block = (b >> 3) * 4 + (xcd & 3);
    int wave = threadIdx.x >> 6, lane = threadIdx.x & 63;
    int node = node_block * 4 + wave;
    if (node >= n) return;
    const unsigned short* base = in + slice * 64;
    float acc = bf1(base[(size_t)node * 128 + lane]);
    int beg = __builtin_amdgcn_readfirstlane(row_off[node]);
    int end = __builtin_amdgcn_readfirstlane(row_off[node + 1]);
    int e = beg;
    for (; (e & 3) && e < end; ++e)
        acc += bf1(base[(size_t)csr_src[e] * 128 + lane]);
    int nmain = (end - e) >> 2;
    if (nmain > 0) {
        const int4* cp = (const int4*)&csr_src[e];
        int4 q = cp[0];
        for (int it = 1; it < nmain; ++it) {
            int4 r = cp[it];
            float v0 = bf1(base[(size_t)q.x * 128 + lane]);
            float v1 = bf1(base[(size_t)q.y * 128 + lane]);
            float v2 = bf1(base[(size_t)q.z * 128 + lane]);
            float v3 = bf1(base[(size_t)q.w * 128 + lane]);
            acc += v0; acc += v1; acc += v2; acc += v3;
            q = r;
        }
        {
            float v0 = bf1(base[(size_t)q.x * 128 + lane]);
            float v1 = bf1(base[(size_t)q.y * 128 + lane]);
            float v2 = bf1(base[(size_t)q.z * 128 + lane]);
            float v3 = bf1(base[(size_t)q.w * 128 + lane]);
            acc += v0; acc += v1; acc += v2; acc += v3;
        }
        e += nmain * 4;
    }
    for (; e < end; ++e)
        acc += bf1(base[(size_t)csr_src[e] * 128 + lane]);
    out[(size_t)node * 128 + slice * 64 + lane] = f2bf(acc * dinv[node]);
}

// ---------------- bf16 MFMA GEMM + bias + ReLU (+optional dinv row-scale), bf16 out ----------------
// C[M,Nc] = relu(A @ B + bias) [* dinv[row] if SCALE], A bf16 [M][K], Bt bf16 [Nc][K].
// 128x128 tile, 4 waves (2x2), each 64x64 via 4x4 v_mfma_f32_16x16x32_bf16.
// Layouts verified (learn_hip m89/m91): A-frag A[m=lane&15][k=quad*8+j]; C/D col=lane&15,row=quad*4+reg.

template<bool SCALE>
__global__ __launch_bounds__(256) void gemm_mfma_bias_relu(
        const unsigned short* __restrict__ A,
        const unsigned short* __restrict__ Bt,
        const float* __restrict__ bias,
        const float* __restrict__ dinv,
        unsigned short* __restrict__ C, int M, int K, int Nc) {
    constexpr int LDT = 40;
    __shared__ unsigned short As[128 * LDT];
    __shared__ unsigned short Bs[128 * LDT];
    int tid = threadIdx.x;
    int lane = tid & 63, wave = tid >> 6;
    int wm = (wave >> 1) * 64, wn = (wave & 1) * 64;
    int bm = blockIdx.x * 128, bn = blockIdx.y * 128;
    int l15 = lane & 15, quad = lane >> 4;

    floatx4 zero = {0.f, 0.f, 0.f, 0.f};
    floatx4 acc[4][4];
    #pragma unroll
    for (int s = 0; s < 4; ++s)
        #pragma unroll
        for (int t = 0; t < 4; ++t) acc[s][t] = zero;

    for (int k0 = 0; k0 < K; k0 += 32) {
        #pragma unroll
        for (int c = tid; c < 512; c += 256) {
            int row = c >> 2, q = c & 3;
            int4 va = {0, 0, 0, 0};
            int gr = bm + row;
            if (gr < M) va = *(const int4*)&A[(size_t)gr * K + k0 + q * 8];
            *(int4*)&As[row * LDT + q * 8] = va;
            int4 vb = *(const int4*)&Bt[(size_t)(bn + row) * K + k0 + q * 8];
            *(int4*)&Bs[row * LDT + q * 8] = vb;
        }
        __syncthreads();
        short8 af[4], bf[4];
        #pragma unroll
        for (int s = 0; s < 4; ++s)
            af[s] = *(const short8*)&As[(wm + s * 16 + l15) * LDT + quad * 8];
        #pragma unroll
        for (int t = 0; t < 4; ++t)
            bf[t] = *(const short8*)&Bs[(wn + t * 16 + l15) * LDT + quad * 8];
        #pragma unroll
        for (int s = 0; s < 4; ++s)
            #pragma unroll
            for (int t = 0; t < 4; ++t)
                acc[s][t] = __builtin_amdgcn_mfma_f32_16x16x32_bf16(af[s], bf[t], acc[s][t], 0, 0, 0);
        __syncthreads();
    }
    #pragma unroll
    for (int s = 0; s < 4; ++s) {
        int row0 = bm + wm + s * 16 + quad * 4;
        #pragma unroll
        for (int t = 0; t < 4; ++t) {
            int col = bn + wn + t * 16 + l15;
            float bb = bias[col];
            #pragma unroll
            for (int r = 0; r < 4; ++r) {
                int row = row0 + r;
                if (row < M) {
                    float o = fmaxf(acc[s][t][r] + bb, 0.f);
                    if constexpr (SCALE) o *= dinv[row];
                    C[(size_t)row * Nc + col] = f2bf(o);
                }
            }
        }
    }
}

// ---------------- pool + head: one block per graph (h2 in bf16) ----------------

__device__ __forceinline__ int lower_bound_i(const int* __restrict__ a, int n, int v) {
    int lo = 0, hi = n;
    while (lo < hi) {
        int mid = (lo + hi) >> 1;
        if (a[mid] < v) lo = mid + 1; else hi = mid;
    }
    return lo;
}

__global__ __launch_bounds__(256) void pool_head(const unsigned short* __restrict__ h,
                                                 const int* __restrict__ batch,
                                                 const float* __restrict__ num_atoms,
                                                 const float* __restrict__ W3, const float* __restrict__ b3,
                                                 const float* __restrict__ W4, const float* __restrict__ b4,
                                                 float* __restrict__ out, int n) {
    int g = blockIdx.x;
    int tid = threadIdx.x;
    __shared__ int s_lo, s_hi;
    if (tid == 0) {
        s_lo = lower_bound_i(batch, n, g);
        s_hi = lower_bound_i(batch, n, g + 1);
    }
    __syncthreads();
    int lo = s_lo, hi = s_hi;
    float sum = 0.f;
    for (int i = lo; i < hi; ++i) sum += bf1(h[(size_t)i * HDIM + tid]);
    float cnt = (float)(hi - lo);
    float pooled = sum / fmaxf(cnt, 1.0f);

    __shared__ float zin[HDIM + 1];
    __shared__ float z[32];
    zin[tid] = pooled;
    if (tid == 0) zin[HDIM] = num_atoms[g];
    __syncthreads();
    if (tid < 32) {
        float a = b3[tid];
        for (int k = 0; k < HDIM + 1; ++k) a = fmaf(zin[k], W3[k * 32 + tid], a);
        z[tid] = fmaxf(a, 0.f);
    }
    __syncthreads();
    if (tid < 4) {
        float a = b4[tid];
        #pragma unroll
        for (int k = 0; k < 32; ++k) a = fmaf(z[k], W4[k * 4 + tid], a);
        out[g * 4 + tid] = a;
    }
}

// ---------------- launch ----------------

extern "C" void kernel_launch(void* const* d_in, const int* in_sizes, int n_in,
                              void* d_out, int out_size, void* d_ws, size_t ws_size,
                              hipStream_t stream) {
    const float* x         = (const float*)d_in[0];
    const int*   edge_idx  = (const int*)d_in[1];
    const int*   batch     = (const int*)d_in[2];
    const float* num_atoms = (const float*)d_in[3];
    const float* W1 = (const float*)d_in[4];
    const float* b1 = (const float*)d_in[5];
    const float* W2 = (const float*)d_in[6];
    const float* b2 = (const float*)d_in[7];
    const float* W3 = (const float*)d_in[8];
    const float* b3 = (const float*)d_in[9];
    const float* W4 = (const float*)d_in[10];
    const float* b4 = (const float*)d_in[11];
    float* out = (float*)d_out;

    const int n = NN, e = EE;
    const int* e_src = edge_idx;
    const int* e_dst = edge_idx + e;

    // workspace (256B aligned). Lifetimes:
    //   P (25.6MB): {x_s [N,128]bf16 ; a0b [N,128]bf16} -> after gemm1, P = a1b [N,256]bf16
    //   Q (25.6MB): h1s [N,256]bf16 (gemm1 out, dead after agg256) -> h2b [N,256]bf16 (gemm2 out)
    char* ws = (char*)d_ws;
    size_t off = 0;
    auto carve = [&](size_t bytes) -> void* {
        void* p = ws + off;
        off = (off + bytes + 255) & ~(size_t)255;
        return p;
    };
    int*   deg_i    = (int*)carve((size_t)n * 4);
    int*   row_off  = (int*)carve((size_t)(n + 1) * 4);
    int*   fill     = (int*)carve((size_t)n * 4);
    int*   blk_sums = (int*)carve((size_t)256 * 4);
    float* dinv     = (float*)carve((size_t)n * 4);
    unsigned short* W1t = (unsigned short*)carve((size_t)FDIM * HDIM * 2);
    unsigned short* W2t = (unsigned short*)carve((size_t)HDIM * HDIM * 2);
    int*   csr_src  = (int*)carve((size_t)e * 4);
    unsigned short* P = (unsigned short*)carve((size_t)n * HDIM * 2);
    unsigned short* Q = (unsigned short*)carve((size_t)n * HDIM * 2);
    unsigned short* x_s  = P;                       // [N,128] bf16 pre-scaled
    unsigned short* a0b  = P + (size_t)n * FDIM;    // [N,128] bf16
    unsigned short* a1b  = P;                       // [N,256] bf16 (x_s/a0b dead)
    unsigned short* h1s  = Q;                       // [N,256] bf16 pre-scaled
    unsigned short* h2b  = Q;                       // [N,256] bf16 (h1s dead after agg256)
    (void)ws_size; (void)n_in; (void)in_sizes; (void)out_size;

    hipMemsetAsync(deg_i, 0, (size_t)n * 4, stream);
    hist_kernel<<<1024, 256, 0, stream>>>(e_dst, deg_i, e);
    scan_part<<<SCAN_NB, 256, 0, stream>>>(deg_i, row_off, blk_sums, dinv, n);
    scan_sums<<<1, 256, 0, stream>>>(blk_sums, SCAN_NB);
    scan_add<<<SCAN_NB, 256, 0, stream>>>(row_off, blk_sums, fill, n, e);
    scatter_kernel<<<1024, 256, 0, stream>>>(e_src, e_dst, row_off, fill, csr_src, e);

    cast_scale_bf16<<<1024, 256, 0, stream>>>(x, dinv, x_s, n * FDIM);
    transpose_cast_bf16<<<(FDIM * HDIM + 255) / 256, 256, 0, stream>>>(W1, W1t, FDIM, HDIM);
    transpose_cast_bf16<<<(HDIM * HDIM + 255) / 256, 256, 0, stream>>>(W2, W2t, HDIM, HDIM);

    int node_blocks = (n + 3) / 4;                 // 12500
    int agg_grid = ((node_blocks + 3) / 4) * 8;    // 25000
    dim3 gemm_grid((n + 127) / 128, HDIM / 128);
    // L1: a0 = dinv*(agg of x_s); h1s = relu(a0 @ W1 + b1) * dinv  (bf16)
    gcn_agg128_sliced<<<agg_grid, 256, 0, stream>>>(x_s, row_off, csr_src, dinv, a0b, n);
    gemm_mfma_bias_relu<true><<<gemm_grid, 256, 0, stream>>>(a0b, W1t, b1, dinv, h1s, n, FDIM, HDIM);
    // L2: a1 = dinv*(agg of h1s); h2b = relu(a1 @ W2 + b2)  (bf16)
    gcn_agg256_sliced<<<agg_grid, 256, 0, stream>>>(h1s, row_off, csr_src, dinv, a1b, n);
    gemm_mfma_bias_relu<false><<<gemm_grid, 256, 0, stream>>>(a1b, W2t, b2, dinv, h2b, n, HDIM, HDIM);
    // pool + head
    pool_head<<<GG, 256, 0, stream>>>(h2b, batch, num_atoms, W3, b3, W4, b4, out, n);
}

// Round 9
// 374.773 us; speedup vs baseline: 1.0882x; 1.0882x over previous
//
#include <hip/hip_runtime.h>
#include <hip/hip_bf16.h>

// GNN: 2-layer GCN (N=50000, E=800000, F=128, H=256) + mean-pool (G=512) + MLP head (257->32->4)
// Identity 1 (linearity): agg-then-GEMM per layer.
// Identity 2 (norm factoring): out[d] = dinv[d]*(sum_e in_s[src] + in_s[d]), in_s = dinv*in,
//   so CSR is src-only (4B/edge) and agg is plain adds.
// R8 post-mortem: 2-way XCD column slicing REGRESSED (per-XCD requested bytes unchanged,
//   12.8MB working set >> 4MB L2 -> capacity misses persist; fetch 190->162MB only).
// R9: revert to R7 full-row wave-per-node agg (proven 57/26us); keep int-only CSR (4 edges
//   per int4), pre-scaled bf16 payloads, bf16 h2. GEMMs: bf16 MFMA 128x128 (R7, verified).

#define NN 50000
#define EE 800000
#define FDIM 128
#define HDIM 256
#define GG 512
#define SCAN_NB ((NN + 255) / 256)

typedef __attribute__((ext_vector_type(8))) short short8;     // 8 bf16 = 4 VGPRs (MFMA A/B frag)
typedef __attribute__((ext_vector_type(4))) float floatx4;    // MFMA C/D frag

__device__ __forceinline__ unsigned short f2bf(float f) {   // RNE
    unsigned u = __float_as_uint(f);
    return (unsigned short)((u + 0x7FFF + ((u >> 16) & 1)) >> 16);
}
__device__ __forceinline__ float bflo(unsigned v) { return __uint_as_float(v << 16); }
__device__ __forceinline__ float bfhi(unsigned v) { return __uint_as_float(v & 0xFFFF0000u); }
__device__ __forceinline__ float bf1(unsigned short v) { return __uint_as_float((unsigned)v << 16); }

// ---------------- prep kernels ----------------

__global__ void hist_kernel(const int* __restrict__ dst, int* __restrict__ deg, int e) {
    int i = blockIdx.x * blockDim.x + threadIdx.x;
    int stride = gridDim.x * blockDim.x;
    for (; i < e; i += stride) atomicAdd(&deg[dst[i]], 1);
}

__global__ __launch_bounds__(256) void scan_part(const int* __restrict__ deg,
                                                 int* __restrict__ row_off,
                                                 int* __restrict__ blk_sums,
                                                 float* __restrict__ dinv, int n) {
    __shared__ int s[256];
    int tid = threadIdx.x;
    int i = blockIdx.x * 256 + tid;
    int v = (i < n) ? deg[i] : 0;
    if (i < n) dinv[i] = rsqrtf((float)v + 1.0f);
    s[tid] = v;
    __syncthreads();
    #pragma unroll
    for (int off = 1; off < 256; off <<= 1) {
        int t = (tid >= off) ? s[tid - off] : 0;
        __syncthreads();
        s[tid] += t;
        __syncthreads();
    }
    if (i < n) row_off[i] = s[tid] - v;
    if (tid == 255) blk_sums[blockIdx.x] = s[255];
}

__global__ __launch_bounds__(256) void scan_sums(int* __restrict__ blk_sums, int nb) {
    __shared__ int s[256];
    int tid = threadIdx.x;
    int v = (tid < nb) ? blk_sums[tid] : 0;
    s[tid] = v;
    __syncthreads();
    #pragma unroll
    for (int off = 1; off < 256; off <<= 1) {
        int t = (tid >= off) ? s[tid - off] : 0;
        __syncthreads();
        s[tid] += t;
        __syncthreads();
    }
    if (tid < nb) blk_sums[tid] = s[tid] - v;
}

__global__ __launch_bounds__(256) void scan_add(int* __restrict__ row_off,
                                                const int* __restrict__ blk_sums,
                                                int* __restrict__ fill, int n, int e) {
    int i = blockIdx.x * 256 + threadIdx.x;
    if (i < n) {
        row_off[i] += blk_sums[blockIdx.x];
        fill[i] = 0;
    }
    if (i == 0) row_off[n] = e;
}

// CSR = src indices only (weights factored out via pre-scaling)
__global__ void scatter_kernel(const int* __restrict__ src, const int* __restrict__ dst,
                               const int* __restrict__ row_off, int* __restrict__ fill,
                               int* __restrict__ csr_src, int e) {
    int i = blockIdx.x * blockDim.x + threadIdx.x;
    int stride = gridDim.x * blockDim.x;
    for (; i < e; i += stride) {
        int s = src[i], d = dst[i];
        int pos = row_off[d] + atomicAdd(&fill[d], 1);
        csr_src[pos] = s;
    }
}

// x_s[i,c] = bf16(x[i,c] * dinv[i]); 4 consecutive elems share a row (128 % 4 == 0)
__global__ void cast_scale_bf16(const float* __restrict__ in, const float* __restrict__ dinv,
                                unsigned short* __restrict__ out, int count) {
    int i = (blockIdx.x * blockDim.x + threadIdx.x) * 4;
    int stride = gridDim.x * blockDim.x * 4;
    for (; i < count; i += stride) {
        float d = dinv[i >> 7];
        float4 v = *(const float4*)&in[i];
        ushort4 o;
        o.x = f2bf(v.x * d); o.y = f2bf(v.y * d); o.z = f2bf(v.z * d); o.w = f2bf(v.w * d);
        *(ushort4*)&out[i] = o;
    }
}

// Wt[n][k] = bf16(W[k][n])
__global__ void transpose_cast_bf16(const float* __restrict__ W, unsigned short* __restrict__ Wt,
                                    int K, int Nc) {
    int idx = blockIdx.x * blockDim.x + threadIdx.x;
    if (idx < K * Nc) {
        int nn = idx / K, k = idx - nn * K;
        Wt[idx] = f2bf(W[(size_t)k * Nc + nn]);
    }
}

// ---------------- GCN aggregation (full-row, wave-per-node; R7 structure) ----------------
// out[d] = bf16(dinv[d] * (in_s[d] + sum_e in_s[src_e])) — in_s pre-scaled bf16.
// int-only CSR: one int4 load covers 4 edges; prefetch next int4.

__global__ __launch_bounds__(256) void gcn_agg256_bf16(const unsigned short* __restrict__ in,
                                                       const int* __restrict__ row_off,
                                                       const int* __restrict__ csr_src,
                                                       const float* __restrict__ dinv,
                                                       unsigned short* __restrict__ out, int n) {
    int wave = threadIdx.x >> 6;
    int lane = threadIdx.x & 63;
    int node = blockIdx.x * 4 + wave;
    if (node >= n) return;
    uint2 hu = *(const uint2*)&in[(size_t)node * 256 + lane * 4];
    float4 acc = {bflo(hu.x), bfhi(hu.x), bflo(hu.y), bfhi(hu.y)};
    int beg = __builtin_amdgcn_readfirstlane(row_off[node]);
    int end = __builtin_amdgcn_readfirstlane(row_off[node + 1]);
    int e = beg;
    for (; (e & 3) && e < end; ++e) {     // align to int4
        uint2 u = *(const uint2*)&in[(size_t)csr_src[e] * 256 + lane * 4];
        acc.x += bflo(u.x); acc.y += bfhi(u.x);
        acc.z += bflo(u.y); acc.w += bfhi(u.y);
    }
    int nmain = (end - e) >> 2;
    if (nmain > 0) {
        const int4* cp = (const int4*)&csr_src[e];
        int4 q = cp[0];
        for (int it = 1; it < nmain; ++it) {
            int4 r = cp[it];                       // prefetch next 4 edges
            uint2 u0 = *(const uint2*)&in[(size_t)q.x * 256 + lane * 4];
            uint2 u1 = *(const uint2*)&in[(size_t)q.y * 256 + lane * 4];
            uint2 u2 = *(const uint2*)&in[(size_t)q.z * 256 + lane * 4];
            uint2 u3 = *(const uint2*)&in[(size_t)q.w * 256 + lane * 4];
            acc.x += bflo(u0.x); acc.y += bfhi(u0.x); acc.z += bflo(u0.y); acc.w += bfhi(u0.y);
            acc.x += bflo(u1.x); acc.y += bfhi(u1.x); acc.z += bflo(u1.y); acc.w += bfhi(u1.y);
            acc.x += bflo(u2.x); acc.y += bfhi(u2.x); acc.z += bflo(u2.y); acc.w += bfhi(u2.y);
            acc.x += bflo(u3.x); acc.y += bfhi(u3.x); acc.z += bflo(u3.y); acc.w += bfhi(u3.y);
            q = r;
        }
        {
            uint2 u0 = *(const uint2*)&in[(size_t)q.x * 256 + lane * 4];
            uint2 u1 = *(const uint2*)&in[(size_t)q.y * 256 + lane * 4];
            uint2 u2 = *(const uint2*)&in[(size_t)q.z * 256 + lane * 4];
            uint2 u3 = *(const uint2*)&in[(size_t)q.w * 256 + lane * 4];
            acc.x += bflo(u0.x); acc.y += bfhi(u0.x); acc.z += bflo(u0.y); acc.w += bfhi(u0.y);
            acc.x += bflo(u1.x); acc.y += bfhi(u1.x); acc.z += bflo(u1.y); acc.w += bfhi(u1.y);
            acc.x += bflo(u2.x); acc.y += bfhi(u2.x); acc.z += bflo(u2.y); acc.w += bfhi(u2.y);
            acc.x += bflo(u3.x); acc.y += bfhi(u3.x); acc.z += bflo(u3.y); acc.w += bfhi(u3.y);
        }
        e += nmain * 4;
    }
    for (; e < end; ++e) {
        uint2 u = *(const uint2*)&in[(size_t)csr_src[e] * 256 + lane * 4];
        acc.x += bflo(u.x); acc.y += bfhi(u.x);
        acc.z += bflo(u.y); acc.w += bfhi(u.y);
    }
    float di = dinv[node];
    ushort4 o;
    o.x = f2bf(acc.x * di); o.y = f2bf(acc.y * di);
    o.z = f2bf(acc.z * di); o.w = f2bf(acc.w * di);
    *(ushort4*)&out[(size_t)node * 256 + lane * 4] = o;
}

__global__ __launch_bounds__(256) void gcn_agg128_bf16(const unsigned short* __restrict__ in,
                                                       const int* __restrict__ row_off,
                                                       const int* __restrict__ csr_src,
                                                       const float* __restrict__ dinv,
                                                       unsigned short* __restrict__ out, int n) {
    int wave = threadIdx.x >> 6;
    int lane = threadIdx.x & 63;
    int node = blockIdx.x * 4 + wave;
    if (node >= n) return;
    unsigned hu = *(const unsigned*)&in[(size_t)node * 128 + lane * 2];
    float2 acc = {bflo(hu), bfhi(hu)};
    int beg = __builtin_amdgcn_readfirstlane(row_off[node]);
    int end = __builtin_amdgcn_readfirstlane(row_off[node + 1]);
    int e = beg;
    for (; (e & 3) && e < end; ++e) {
        unsigned u = *(const unsigned*)&in[(size_t)csr_src[e] * 128 + lane * 2];
        acc.x += bflo(u); acc.y += bfhi(u);
    }
    int nmain = (end - e) >> 2;
    if (nmain > 0) {
        const int4* cp = (const int4*)&csr_src[e];
        int4 q = cp[0];
        for (int it = 1; it < nmain; ++it) {
            int4 r = cp[it];
            unsigned u0 = *(const unsigned*)&in[(size_t)q.x * 128 + lane * 2];
            unsigned u1 = *(const unsigned*)&in[(size_t)q.y * 128 + lane * 2];
            unsigned u2 = *(const unsigned*)&in[(size_t)q.z * 128 + lane * 2];
            unsigned u3 = *(const unsigned*)&in[(size_t)q.w * 128 + lane * 2];
            acc.x += bflo(u0); acc.y += bfhi(u0);
            acc.x += bflo(u1); acc.y += bfhi(u1);
            acc.x += bflo(u2); acc.y += bfhi(u2);
            acc.x += bflo(u3); acc.y += bfhi(u3);
            q = r;
        }
        {
            unsigned u0 = *(const unsigned*)&in[(size_t)q.x * 128 + lane * 2];
            unsigned u1 = *(const unsigned*)&in[(size_t)q.y * 128 + lane * 2];
            unsigned u2 = *(const unsigned*)&in[(size_t)q.z * 128 + lane * 2];
            unsigned u3 = *(const unsigned*)&in[(size_t)q.w * 128 + lane * 2];
            acc.x += bflo(u0); acc.y += bfhi(u0);
            acc.x += bflo(u1); acc.y += bfhi(u1);
            acc.x += bflo(u2); acc.y += bfhi(u2);
            acc.x += bflo(u3); acc.y += bfhi(u3);
        }
        e += nmain * 4;
    }
    for (; e < end; ++e) {
        unsigned u = *(const unsigned*)&in[(size_t)csr_src[e] * 128 + lane * 2];
        acc.x += bflo(u); acc.y += bfhi(u);
    }
    float di = dinv[node];
    unsigned o = (unsigned)f2bf(acc.x * di) | ((unsigned)f2bf(acc.y * di) << 16);
    *(unsigned*)&out[(size_t)node * 128 + lane * 2] = o;
}

// ---------------- bf16 MFMA GEMM + bias + ReLU (+optional dinv row-scale), bf16 out ----------------
// C[M,Nc] = relu(A @ B + bias) [* dinv[row] if SCALE], A bf16 [M][K], Bt bf16 [Nc][K].
// 128x128 tile, 4 waves (2x2), each 64x64 via 4x4 v_mfma_f32_16x16x32_bf16.
// Layouts verified (learn_hip m89/m91): A-frag A[m=lane&15][k=quad*8+j]; C/D col=lane&15,row=quad*4+reg.

template<bool SCALE>
__global__ __launch_bounds__(256) void gemm_mfma_bias_relu(
        const unsigned short* __restrict__ A,
        const unsigned short* __restrict__ Bt,
        const float* __restrict__ bias,
        const float* __restrict__ dinv,
        unsigned short* __restrict__ C, int M, int K, int Nc) {
    constexpr int LDT = 40;
    __shared__ unsigned short As[128 * LDT];
    __shared__ unsigned short Bs[128 * LDT];
    int tid = threadIdx.x;
    int lane = tid & 63, wave = tid >> 6;
    int wm = (wave >> 1) * 64, wn = (wave & 1) * 64;
    int bm = blockIdx.x * 128, bn = blockIdx.y * 128;
    int l15 = lane & 15, quad = lane >> 4;

    floatx4 zero = {0.f, 0.f, 0.f, 0.f};
    floatx4 acc[4][4];
    #pragma unroll
    for (int s = 0; s < 4; ++s)
        #pragma unroll
        for (int t = 0; t < 4; ++t) acc[s][t] = zero;

    for (int k0 = 0; k0 < K; k0 += 32) {
        #pragma unroll
        for (int c = tid; c < 512; c += 256) {
            int row = c >> 2, q = c & 3;
            int4 va = {0, 0, 0, 0};
            int gr = bm + row;
            if (gr < M) va = *(const int4*)&A[(size_t)gr * K + k0 + q * 8];
            *(int4*)&As[row * LDT + q * 8] = va;
            int4 vb = *(const int4*)&Bt[(size_t)(bn + row) * K + k0 + q * 8];
            *(int4*)&Bs[row * LDT + q * 8] = vb;
        }
        __syncthreads();
        short8 af[4], bf[4];
        #pragma unroll
        for (int s = 0; s < 4; ++s)
            af[s] = *(const short8*)&As[(wm + s * 16 + l15) * LDT + quad * 8];
        #pragma unroll
        for (int t = 0; t < 4; ++t)
            bf[t] = *(const short8*)&Bs[(wn + t * 16 + l15) * LDT + quad * 8];
        #pragma unroll
        for (int s = 0; s < 4; ++s)
            #pragma unroll
            for (int t = 0; t < 4; ++t)
                acc[s][t] = __builtin_amdgcn_mfma_f32_16x16x32_bf16(af[s], bf[t], acc[s][t], 0, 0, 0);
        __syncthreads();
    }
    #pragma unroll
    for (int s = 0; s < 4; ++s) {
        int row0 = bm + wm + s * 16 + quad * 4;
        #pragma unroll
        for (int t = 0; t < 4; ++t) {
            int col = bn + wn + t * 16 + l15;
            float bb = bias[col];
            #pragma unroll
            for (int r = 0; r < 4; ++r) {
                int row = row0 + r;
                if (row < M) {
                    float o = fmaxf(acc[s][t][r] + bb, 0.f);
                    if constexpr (SCALE) o *= dinv[row];
                    C[(size_t)row * Nc + col] = f2bf(o);
                }
            }
        }
    }
}

// ---------------- pool + head: one block per graph (h2 in bf16) ----------------

__device__ __forceinline__ int lower_bound_i(const int* __restrict__ a, int n, int v) {
    int lo = 0, hi = n;
    while (lo < hi) {
        int mid = (lo + hi) >> 1;
        if (a[mid] < v) lo = mid + 1; else hi = mid;
    }
    return lo;
}

__global__ __launch_bounds__(256) void pool_head(const unsigned short* __restrict__ h,
                                                 const int* __restrict__ batch,
                                                 const float* __restrict__ num_atoms,
                                                 const float* __restrict__ W3, const float* __restrict__ b3,
                                                 const float* __restrict__ W4, const float* __restrict__ b4,
                                                 float* __restrict__ out, int n) {
    int g = blockIdx.x;
    int tid = threadIdx.x;
    __shared__ int s_lo, s_hi;
    if (tid == 0) {
        s_lo = lower_bound_i(batch, n, g);
        s_hi = lower_bound_i(batch, n, g + 1);
    }
    __syncthreads();
    int lo = s_lo, hi = s_hi;
    float sum = 0.f;
    for (int i = lo; i < hi; ++i) sum += bf1(h[(size_t)i * HDIM + tid]);
    float cnt = (float)(hi - lo);
    float pooled = sum / fmaxf(cnt, 1.0f);

    __shared__ float zin[HDIM + 1];
    __shared__ float z[32];
    zin[tid] = pooled;
    if (tid == 0) zin[HDIM] = num_atoms[g];
    __syncthreads();
    if (tid < 32) {
        float a = b3[tid];
        for (int k = 0; k < HDIM + 1; ++k) a = fmaf(zin[k], W3[k * 32 + tid], a);
        z[tid] = fmaxf(a, 0.f);
    }
    __syncthreads();
    if (tid < 4) {
        float a = b4[tid];
        #pragma unroll
        for (int k = 0; k < 32; ++k) a = fmaf(z[k], W4[k * 4 + tid], a);
        out[g * 4 + tid] = a;
    }
}

// ---------------- launch ----------------

extern "C" void kernel_launch(void* const* d_in, const int* in_sizes, int n_in,
                              void* d_out, int out_size, void* d_ws, size_t ws_size,
                              hipStream_t stream) {
    const float* x         = (const float*)d_in[0];
    const int*   edge_idx  = (const int*)d_in[1];
    const int*   batch     = (const int*)d_in[2];
    const float* num_atoms = (const float*)d_in[3];
    const float* W1 = (const float*)d_in[4];
    const float* b1 = (const float*)d_in[5];
    const float* W2 = (const float*)d_in[6];
    const float* b2 = (const float*)d_in[7];
    const float* W3 = (const float*)d_in[8];
    const float* b3 = (const float*)d_in[9];
    const float* W4 = (const float*)d_in[10];
    const float* b4 = (const float*)d_in[11];
    float* out = (float*)d_out;

    const int n = NN, e = EE;
    const int* e_src = edge_idx;
    const int* e_dst = edge_idx + e;

    // workspace (256B aligned). Lifetimes:
    //   P (25.6MB): {x_s [N,128]bf16 ; a0b [N,128]bf16} -> after gemm1, P = a1b [N,256]bf16
    //   Q (25.6MB): h1s [N,256]bf16 (gemm1 out, dead after agg256) -> h2b [N,256]bf16 (gemm2 out)
    char* ws = (char*)d_ws;
    size_t off = 0;
    auto carve = [&](size_t bytes) -> void* {
        void* p = ws + off;
        off = (off + bytes + 255) & ~(size_t)255;
        return p;
    };
    int*   deg_i    = (int*)carve((size_t)n * 4);
    int*   row_off  = (int*)carve((size_t)(n + 1) * 4);
    int*   fill     = (int*)carve((size_t)n * 4);
    int*   blk_sums = (int*)carve((size_t)256 * 4);
    float* dinv     = (float*)carve((size_t)n * 4);
    unsigned short* W1t = (unsigned short*)carve((size_t)FDIM * HDIM * 2);
    unsigned short* W2t = (unsigned short*)carve((size_t)HDIM * HDIM * 2);
    int*   csr_src  = (int*)carve((size_t)e * 4);
    unsigned short* P = (unsigned short*)carve((size_t)n * HDIM * 2);
    unsigned short* Q = (unsigned short*)carve((size_t)n * HDIM * 2);
    unsigned short* x_s  = P;                       // [N,128] bf16 pre-scaled
    unsigned short* a0b  = P + (size_t)n * FDIM;    // [N,128] bf16
    unsigned short* a1b  = P;                       // [N,256] bf16 (x_s/a0b dead)
    unsigned short* h1s  = Q;                       // [N,256] bf16 pre-scaled
    unsigned short* h2b  = Q;                       // [N,256] bf16 (h1s dead after agg256)
    (void)ws_size; (void)n_in; (void)in_sizes; (void)out_size;

    hipMemsetAsync(deg_i, 0, (size_t)n * 4, stream);
    hist_kernel<<<1024, 256, 0, stream>>>(e_dst, deg_i, e);
    scan_part<<<SCAN_NB, 256, 0, stream>>>(deg_i, row_off, blk_sums, dinv, n);
    scan_sums<<<1, 256, 0, stream>>>(blk_sums, SCAN_NB);
    scan_add<<<SCAN_NB, 256, 0, stream>>>(row_off, blk_sums, fill, n, e);
    scatter_kernel<<<1024, 256, 0, stream>>>(e_src, e_dst, row_off, fill, csr_src, e);

    cast_scale_bf16<<<1024, 256, 0, stream>>>(x, dinv, x_s, n * FDIM);
    transpose_cast_bf16<<<(FDIM * HDIM + 255) / 256, 256, 0, stream>>>(W1, W1t, FDIM, HDIM);
    transpose_cast_bf16<<<(HDIM * HDIM + 255) / 256, 256, 0, stream>>>(W2, W2t, HDIM, HDIM);

    dim3 gemm_grid((n + 127) / 128, HDIM / 128);
    // L1: a0 = dinv*(agg of x_s); h1s = relu(a0 @ W1 + b1) * dinv  (bf16)
    gcn_agg128_bf16<<<(n + 3) / 4, 256, 0, stream>>>(x_s, row_off, csr_src, dinv, a0b, n);
    gemm_mfma_bias_relu<true><<<gemm_grid, 256, 0, stream>>>(a0b, W1t, b1, dinv, h1s, n, FDIM, HDIM);
    // L2: a1 = dinv*(agg of h1s); h2b = relu(a1 @ W2 + b2)  (bf16)
    gcn_agg256_bf16<<<(n + 3) / 4, 256, 0, stream>>>(h1s, row_off, csr_src, dinv, a1b, n);
    gemm_mfma_bias_relu<false><<<gemm_grid, 256, 0, stream>>>(a1b, W2t, b2, dinv, h2b, n, HDIM, HDIM);
    // pool + head
    pool_head<<<GG, 256, 0, stream>>>(h2b, batch, num_atoms, W3, b3, W4, b4, out, n);
}